// Round 1
// baseline (3693.933 us; speedup 1.0000x reference)
//
#include <hip/hip_runtime.h>
#include <hip/hip_bf16.h>
#include <math.h>

#define B_   1024
#define ZD_  256
#define HD_  1024
#define L_   32
#define NW_  64
#define XD_  1024
#define KA_  1280   // concat K: 1024 (h) + 256 (z)
#define THD_ 3072

typedef __attribute__((ext_vector_type(8))) short short8;
typedef __attribute__((ext_vector_type(4))) float f32x4;

__device__ __forceinline__ unsigned short f2bf(float f) {
  unsigned int u = __float_as_uint(f);
  u += 0x7fffu + ((u >> 16) & 1u);   // RNE
  return (unsigned short)(u >> 16);
}
__device__ __forceinline__ float sig_(float x) { return 1.0f / (1.0f + __expf(-x)); }
__device__ __forceinline__ float tanh_(float x) {
  float e = __expf(2.0f * x);
  return 1.0f - 2.0f / (e + 1.0f);
}
__device__ __forceinline__ f32x4 mfma16(short8 a, short8 b, f32x4 c) {
  return __builtin_amdgcn_mfma_f32_16x16x32_bf16(a, b, c, 0, 0, 0);
}
__device__ __forceinline__ short8 pack8(f32x4 f0, f32x4 f1) {
  short8 v;
  v[0] = (short)f2bf(f0[0]); v[1] = (short)f2bf(f0[1]);
  v[2] = (short)f2bf(f0[2]); v[3] = (short)f2bf(f0[3]);
  v[4] = (short)f2bf(f1[0]); v[5] = (short)f2bf(f1[1]);
  v[6] = (short)f2bf(f1[2]); v[7] = (short)f2bf(f1[3]);
  return v;
}

// ---------------------------------------------------------------------------
// Setup: A-buffer (h||z, both slabs), h32 zero, Wih[:, :256] -> bf16 pre-cast
// ---------------------------------------------------------------------------
__global__ __launch_bounds__(256) void setup_kernel(
    const float* __restrict__ z, const float* __restrict__ Wih,
    unsigned short* __restrict__ Abuf, float* __restrict__ h32,
    unsigned short* __restrict__ WihzB) {
  long idx = (long)blockIdx.x * 256 + threadIdx.x;
  const long N1 = (long)B_ * KA_;            // 1,310,720
  const long N2 = (long)L_ * THD_ * ZD_;     // 25,165,824
  if (idx < N1) {
    int b = (int)(idx / KA_), c = (int)(idx % KA_);
    unsigned short v = 0;
    if (c >= HD_) v = f2bf(z[(size_t)b * ZD_ + (c - HD_)]);
    Abuf[idx] = v;
    Abuf[N1 + idx] = v;                      // second slab
    if (c < HD_) h32[(size_t)b * HD_ + c] = 0.f;
  } else if (idx < N1 + N2) {
    long i2 = idx - N1;
    int c = (int)(i2 & 255);
    long jj = i2 >> 8;                       // l*3HD + j
    int l = (int)(jj / THD_), j = (int)(jj % THD_);
    WihzB[i2] = f2bf(Wih[((size_t)l * THD_ + j) * 257 + c]);
  }
}

// ---------------------------------------------------------------------------
// One GRU step: fused [h|z] @ [Whh|Wih]^T + full gate epilogue.
// Grid (16 n-tiles, 16 m-tiles), 256 thr. Block tile 64m x 64n x 3 gates.
// n-gate kept as two accumulators (hn for k<1024, xn for k>=1024).
// ---------------------------------------------------------------------------
__global__ __launch_bounds__(256) void step_kernel(
    const unsigned short* __restrict__ Acur,   // [B, KA] bf16
    unsigned short* __restrict__ Anext,        // [B, KA] bf16 (writes h part)
    const float* __restrict__ Whh,             // [L,3HD,HD] fp32
    const float* __restrict__ Wih,             // [L,3HD,257] fp32 (col 256 + epilogue)
    const unsigned short* __restrict__ WihzB,  // [L,3HD,256] bf16
    const float* __restrict__ bih, const float* __restrict__ bhh,
    const float* __restrict__ tmat,            // [B, L]
    const float* __restrict__ eps,             // [L, B, HD]
    float* __restrict__ h32,                   // [B, HD] fp32
    unsigned short* __restrict__ hist,         // [L, B, HD] bf16
    int l) {
  __shared__ __align__(16) unsigned short ldsA[8 * 65 * 8];          // [kg][m(pad65)][8]
  __shared__ __align__(16) unsigned short ldsB[3 * 8 * 65 * 8];      // [g*8+kg][n(pad65)][8]

  const int tid = threadIdx.x;
  const int lane = tid & 63;
  const int w = tid >> 6;
  const int wm = w & 1, wn = w >> 1;
  const int nb = blockIdx.x * 64;
  const int mb = blockIdx.y * 64;

  const float* WhhL = Whh + (size_t)l * THD_ * HD_;
  const float* WihL = Wih + (size_t)l * THD_ * 257;
  const unsigned short* WihzL = WihzB + (size_t)l * THD_ * ZD_;
  const float* bihL = bih + l * THD_;
  const float* bhhL = bhh + l * THD_;
  const float* epsL = eps + (size_t)l * B_ * HD_;
  unsigned short* histL = hist + (size_t)l * B_ * HD_;

  f32x4 zf = {0.f, 0.f, 0.f, 0.f};
  f32x4 accR[2][2], accU[2][2], accHN[2][2], accXN[2][2];
#pragma unroll
  for (int i = 0; i < 2; ++i)
#pragma unroll
    for (int j = 0; j < 2; ++j) { accR[i][j] = zf; accU[i][j] = zf; accHN[i][j] = zf; accXN[i][j] = zf; }

  const int skg = tid & 7;      // staging k-group
  const int sr0 = tid >> 3;     // staging row 0..31

  for (int kt = 0; kt < 20; ++kt) {
    const int k0 = kt * 64;
    const bool phaseH = (kt < 16);
    // ---- stage A tile (bf16 source) ----
#pragma unroll
    for (int rep = 0; rep < 2; ++rep) {
      int m = sr0 + rep * 32;
      short8 v = *reinterpret_cast<const short8*>(Acur + (size_t)(mb + m) * KA_ + k0 + skg * 8);
      *reinterpret_cast<short8*>(&ldsA[((size_t)skg * 65 + m) * 8]) = v;
    }
    // ---- stage B tiles: 3 gates ----
#pragma unroll
    for (int g = 0; g < 3; ++g) {
#pragma unroll
      for (int rep = 0; rep < 2; ++rep) {
        int n = sr0 + rep * 32;
        int j = g * HD_ + nb + n;
        short8 v;
        if (phaseH) {
          const float* src = WhhL + (size_t)j * HD_ + k0 + skg * 8;
          f32x4 f0 = *reinterpret_cast<const f32x4*>(src);
          f32x4 f1 = *reinterpret_cast<const f32x4*>(src + 4);
          v = pack8(f0, f1);
        } else {
          v = *reinterpret_cast<const short8*>(WihzL + (size_t)j * ZD_ + (k0 - HD_) + skg * 8);
        }
        *reinterpret_cast<short8*>(&ldsB[((size_t)(g * 8 + skg) * 65 + n) * 8]) = v;
      }
    }
    __syncthreads();
    // ---- compute ----
    const int q = lane >> 4, cc = lane & 15;
#pragma unroll
    for (int ks = 0; ks < 2; ++ks) {
      const int kq = ks * 4 + q;
      short8 a0 = *(const short8*)&ldsA[((size_t)kq * 65 + wm * 32 + cc) * 8];
      short8 a1 = *(const short8*)&ldsA[((size_t)kq * 65 + wm * 32 + 16 + cc) * 8];
#pragma unroll
      for (int g = 0; g < 3; ++g) {
        short8 b0 = *(const short8*)&ldsB[((size_t)(g * 8 + kq) * 65 + wn * 32 + cc) * 8];
        short8 b1 = *(const short8*)&ldsB[((size_t)(g * 8 + kq) * 65 + wn * 32 + 16 + cc) * 8];
        if (g == 0) {
          accR[0][0] = mfma16(a0, b0, accR[0][0]); accR[0][1] = mfma16(a0, b1, accR[0][1]);
          accR[1][0] = mfma16(a1, b0, accR[1][0]); accR[1][1] = mfma16(a1, b1, accR[1][1]);
        } else if (g == 1) {
          accU[0][0] = mfma16(a0, b0, accU[0][0]); accU[0][1] = mfma16(a0, b1, accU[0][1]);
          accU[1][0] = mfma16(a1, b0, accU[1][0]); accU[1][1] = mfma16(a1, b1, accU[1][1]);
        } else if (phaseH) {
          accHN[0][0] = mfma16(a0, b0, accHN[0][0]); accHN[0][1] = mfma16(a0, b1, accHN[0][1]);
          accHN[1][0] = mfma16(a1, b0, accHN[1][0]); accHN[1][1] = mfma16(a1, b1, accHN[1][1]);
        } else {
          accXN[0][0] = mfma16(a0, b0, accXN[0][0]); accXN[0][1] = mfma16(a0, b1, accXN[0][1]);
          accXN[1][0] = mfma16(a1, b0, accXN[1][0]); accXN[1][1] = mfma16(a1, b1, accXN[1][1]);
        }
      }
    }
    __syncthreads();
  }

  // ---- epilogue: gates + state update ----
  const int q = lane >> 4, cc = lane & 15;
  const float std_ = 1.0025031f;  // exp(0.5*0.005)
#pragma unroll
  for (int j = 0; j < 2; ++j) {
    int n = nb + wn * 32 + j * 16 + cc;
    int jr = n, ju = HD_ + n, jn = 2 * HD_ + n;
    float wt_r = WihL[(size_t)jr * 257 + 256];
    float wt_u = WihL[(size_t)ju * 257 + 256];
    float wt_n = WihL[(size_t)jn * 257 + 256];
    float br = bihL[jr] + bhhL[jr];
    float bu = bihL[ju] + bhhL[ju];
    float bxn = bihL[jn], bhn = bhhL[jn];
#pragma unroll
    for (int i = 0; i < 2; ++i) {
#pragma unroll
      for (int r = 0; r < 4; ++r) {
        int m = mb + wm * 32 + i * 16 + q * 4 + r;
        float tb = tmat[(size_t)m * L_ + l];
        float rv = sig_(accR[i][j][r] + tb * wt_r + br);
        float uv = sig_(accU[i][j][r] + tb * wt_u + bu);
        float nv = tanh_(accXN[i][j][r] + tb * wt_n + bxn + rv * (accHN[i][j][r] + bhn));
        size_t o = (size_t)m * HD_ + n;
        float hold = h32[o];
        float hnew = (1.0f - uv) * nv + uv * hold + std_ * epsL[o];
        h32[o] = hnew;
        unsigned short hb = f2bf(hnew);
        Anext[(size_t)m * KA_ + n] = hb;
        histL[o] = hb;
      }
    }
  }
}

// ---------------------------------------------------------------------------
// Generic batched GEMM (A bf16 [M,K] K-major, B fp32 [N,K] K-major, cvt in
// staging) with epilogue: 0 = relu->bf16, 1 = sigmoid->f32, 2 = sigmoid->f32
// transposed [N,B,L] write.
// ---------------------------------------------------------------------------
template <int BM, int BN, int EPI>
__global__ __launch_bounds__(256) void gemm_epi_kernel(
    const unsigned short* __restrict__ Abase, long strideA, int lda,
    const float* __restrict__ Bbase, long strideB, int ldb,
    const float* __restrict__ biasBase, int strideBias,
    float* __restrict__ outBase, long strideOut, int ldo, int K) {
  constexpr int MI = BM / 32, NJ = BN / 32;
  __shared__ __align__(16) unsigned short ldsA[8 * (BM + 1) * 8];
  __shared__ __align__(16) unsigned short ldsB[8 * (BN + 1) * 8];
  const int tid = threadIdx.x, lane = tid & 63, w = tid >> 6;
  const int wm = w & 1, wn = w >> 1;
  const int nb = blockIdx.x * BN, mb = blockIdx.y * BM;
  const int lz = blockIdx.z;
  const unsigned short* A = Abase + (long)lz * strideA;
  const float* Bw = Bbase + (long)lz * strideB;
  const float* bias = biasBase + (long)lz * strideBias;

  f32x4 zf = {0.f, 0.f, 0.f, 0.f};
  f32x4 acc[MI][NJ];
#pragma unroll
  for (int i = 0; i < MI; ++i)
#pragma unroll
    for (int j = 0; j < NJ; ++j) acc[i][j] = zf;

  const int skg = tid & 7, sr0 = tid >> 3;
  for (int kt = 0; kt < K / 64; ++kt) {
    const int k0 = kt * 64;
#pragma unroll
    for (int rep = 0; rep < BM / 32; ++rep) {
      int m = sr0 + rep * 32;
      short8 v = *reinterpret_cast<const short8*>(A + (size_t)(mb + m) * lda + k0 + skg * 8);
      *reinterpret_cast<short8*>(&ldsA[((size_t)skg * (BM + 1) + m) * 8]) = v;
    }
#pragma unroll
    for (int rep = 0; rep < BN / 32; ++rep) {
      int n = sr0 + rep * 32;
      const float* src = Bw + (size_t)(nb + n) * ldb + k0 + skg * 8;
      f32x4 f0 = *reinterpret_cast<const f32x4*>(src);
      f32x4 f1 = *reinterpret_cast<const f32x4*>(src + 4);
      *reinterpret_cast<short8*>(&ldsB[((size_t)skg * (BN + 1) + n) * 8]) = pack8(f0, f1);
    }
    __syncthreads();
    const int q = lane >> 4, cc = lane & 15;
#pragma unroll
    for (int ks = 0; ks < 2; ++ks) {
      const int kq = ks * 4 + q;
      short8 a[MI];
#pragma unroll
      for (int i = 0; i < MI; ++i)
        a[i] = *(const short8*)&ldsA[((size_t)kq * (BM + 1) + wm * (BM / 2) + i * 16 + cc) * 8];
      short8 bfr[NJ];
#pragma unroll
      for (int j = 0; j < NJ; ++j)
        bfr[j] = *(const short8*)&ldsB[((size_t)kq * (BN + 1) + wn * (BN / 2) + j * 16 + cc) * 8];
#pragma unroll
      for (int i = 0; i < MI; ++i)
#pragma unroll
        for (int j = 0; j < NJ; ++j) acc[i][j] = mfma16(a[i], bfr[j], acc[i][j]);
    }
    __syncthreads();
  }
  const int q = lane >> 4, cc = lane & 15;
#pragma unroll
  for (int j = 0; j < NJ; ++j) {
    int n = nb + wn * (BN / 2) + j * 16 + cc;
    float bv = bias[n];
#pragma unroll
    for (int i = 0; i < MI; ++i) {
#pragma unroll
      for (int r = 0; r < 4; ++r) {
        int m = mb + wm * (BM / 2) + i * 16 + q * 4 + r;
        float v = acc[i][j][r] + bv;
        if (EPI == 0) {
          v = fmaxf(v, 0.f);
          reinterpret_cast<unsigned short*>(outBase)[(long)lz * strideOut + (size_t)m * ldo + n] = f2bf(v);
        } else if (EPI == 1) {
          outBase[(size_t)m * ldo + n] = sig_(v);
        } else {
          outBase[((size_t)n * B_ + m) * L_ + lz] = sig_(v);
        }
      }
    }
  }
}

// ---------------------------------------------------------------------------
extern "C" void kernel_launch(void* const* d_in, const int* in_sizes, int n_in,
                              void* d_out, int out_size, void* d_ws, size_t ws_size,
                              hipStream_t stream) {
  const float* z    = (const float*)d_in[0];
  const float* tmat = (const float*)d_in[1];
  const float* eps  = (const float*)d_in[2];
  const float* Wih  = (const float*)d_in[3];
  const float* Whh  = (const float*)d_in[4];
  const float* bih  = (const float*)d_in[5];
  const float* bhh  = (const float*)d_in[6];
  const float* pW1  = (const float*)d_in[7];
  const float* pb1  = (const float*)d_in[8];
  const float* pW2  = (const float*)d_in[9];
  const float* pb2  = (const float*)d_in[10];
  const float* recW = (const float*)d_in[11];
  const float* recb = (const float*)d_in[12];
  float* out = (float*)d_out;

  char* ws = (char*)d_ws;
  unsigned short* Abuf  = (unsigned short*)(ws);              // 2*B*KA*2      = 5,242,880
  float*          h32   = (float*)(ws + 5242880);             // B*HD*4        = 4,194,304
  unsigned short* hist  = (unsigned short*)(ws + 9437184);    // L*B*HD*2      = 67,108,864
  unsigned short* act   = (unsigned short*)(ws + 76546048);   // L*B*HD*2      = 67,108,864
  unsigned short* WihzB = (unsigned short*)(ws + 143654912);  // L*3HD*256*2   = 50,331,648
  // total: 193,986,560 bytes

  {
    long total = (long)B_ * KA_ + (long)L_ * THD_ * ZD_;
    int blocks = (int)((total + 255) / 256);
    setup_kernel<<<blocks, 256, 0, stream>>>(z, Wih, Abuf, h32, WihzB);
  }
  for (int l = 0; l < L_; ++l) {
    const unsigned short* Acur = Abuf + (size_t)(l & 1) * B_ * KA_;
    unsigned short* Anext      = Abuf + (size_t)((l + 1) & 1) * B_ * KA_;
    step_kernel<<<dim3(16, 16), 256, 0, stream>>>(Acur, Anext, Whh, Wih, WihzB,
                                                  bih, bhh, tmat, eps, h32, hist, l);
  }
  // MLP layer 1: act = relu(hist @ W1^T + b1), batched over L
  gemm_epi_kernel<128, 128, 0><<<dim3(8, 8, L_), 256, 0, stream>>>(
      hist, (long)B_ * HD_, HD_, pW1, (long)HD_ * HD_, HD_, pb1, HD_,
      (float*)act, (long)B_ * HD_, HD_, HD_);
  // MLP layer 2: preds -> transposed [NW, B, L] region of d_out
  gemm_epi_kernel<128, 64, 2><<<dim3(1, 8, L_), 256, 0, stream>>>(
      act, (long)B_ * HD_, HD_, pW2, (long)NW_ * HD_, HD_, pb2, NW_,
      out + (size_t)B_ * XD_, 0, 0, HD_);
  // recon = sigmoid(h_T @ recW^T + recb)
  gemm_epi_kernel<128, 128, 1><<<dim3(8, 8, 1), 256, 0, stream>>>(
      hist + (size_t)(L_ - 1) * B_ * HD_, 0, HD_, recW, 0, HD_, recb, 0,
      out, 0, XD_, HD_);
}

// Round 2
// 2239.173 us; speedup vs baseline: 1.6497x; 1.6497x over previous
//
#include <hip/hip_runtime.h>
#include <hip/hip_bf16.h>
#include <math.h>

#define B_   1024
#define ZD_  256
#define HD_  1024
#define L_   32
#define NW_  64
#define XD_  1024
#define KA_  1280   // concat K: 1024 (h) + 256 (z)
#define THD_ 3072
#define NB_  4096   // augmented N: r, u, hn, xn

typedef __attribute__((ext_vector_type(8))) short short8;
typedef __attribute__((ext_vector_type(4))) float f32x4;

__device__ __forceinline__ unsigned short f2bf(float f) {
  unsigned int u = __float_as_uint(f);
  u += 0x7fffu + ((u >> 16) & 1u);   // RNE
  return (unsigned short)(u >> 16);
}
__device__ __forceinline__ float sig_(float x) { return 1.0f / (1.0f + __expf(-x)); }
__device__ __forceinline__ float tanh_(float x) {
  float e = __expf(2.0f * x);
  return 1.0f - 2.0f / (e + 1.0f);
}
__device__ __forceinline__ f32x4 mfma16(short8 a, short8 b, f32x4 c) {
  return __builtin_amdgcn_mfma_f32_16x16x32_bf16(a, b, c, 0, 0, 0);
}
__device__ __forceinline__ short8 pack8(f32x4 f0, f32x4 f1) {
  short8 v;
  v[0] = (short)f2bf(f0[0]); v[1] = (short)f2bf(f0[1]);
  v[2] = (short)f2bf(f0[2]); v[3] = (short)f2bf(f0[3]);
  v[4] = (short)f2bf(f1[0]); v[5] = (short)f2bf(f1[1]);
  v[6] = (short)f2bf(f1[2]); v[7] = (short)f2bf(f1[3]);
  return v;
}
// async 16B global -> LDS (lane-linear dest: wave base + lane*16)
__device__ __forceinline__ void async_load16(const void* g, void* l) {
  __builtin_amdgcn_global_load_lds(
      (const __attribute__((address_space(1))) unsigned int*)g,
      (__attribute__((address_space(3))) unsigned int*)l, 16, 0, 0);
}

// ---------------------------------------------------------------------------
// Setup 1: build Bfull [L][4096][1280] bf16 from Whh fp32 + Wih fp32.
// Rows: [0,2048) = r,u: [Whh | Wihz]; [2048,3072) = hn: Whh only (k<1024);
// [3072,4096) = xn: Wihz only (k>=1024). Structural zeros never written
// (GEMM skips those kt ranges).
// ---------------------------------------------------------------------------
#define UL_R1 327680   // 2048*160
#define UL_R2 131072   // 1024*128
#define UL_R3 32768    // 1024*32
#define UL_   491520   // per-layer short8 units

__global__ __launch_bounds__(256) void cast_bfull_kernel(
    const float* __restrict__ Whh, const float* __restrict__ Wih,
    unsigned short* __restrict__ Bfull) {
  long u = (long)blockIdx.x * 256 + threadIdx.x;
  int l = (int)(u / UL_);
  int u2 = (int)(u % UL_);
  int j, slot;       // row in [0,4096), k-group slot in [0,160)
  if (u2 < UL_R1) { j = u2 / 160; slot = u2 % 160; }
  else if (u2 < UL_R1 + UL_R2) { int t = u2 - UL_R1; j = 2048 + t / 128; slot = t % 128; }
  else { int t = u2 - UL_R1 - UL_R2; j = 3072 + t / 32; slot = 128 + (t % 32); }
  int k0 = slot * 8;
  short8 v;
  if (k0 < 1024) {
    const float* src = Whh + ((size_t)l * THD_ + j) * HD_ + k0;
    v = pack8(*reinterpret_cast<const f32x4*>(src),
              *reinterpret_cast<const f32x4*>(src + 4));
  } else {
    int jw = (j >= 3072) ? (j - 1024) : j;     // xn rows map to Wih rows 2048..3071
    const float* src = Wih + ((size_t)l * THD_ + jw) * 257 + (k0 - 1024);
#pragma unroll
    for (int i = 0; i < 8; ++i) v[i] = (short)f2bf(src[i]);
  }
  *reinterpret_cast<short8*>(Bfull + (((size_t)l * NB_ + j) * 160 + slot) * 8) = v;
}

// ---------------------------------------------------------------------------
// Setup 2: cast pW1 / pW2 (padded to 128 rows) / recW to bf16.
// ---------------------------------------------------------------------------
#define U_PW1 4194304   // 32*1024*1024/8
#define U_PW2 262144    // 32*64*1024/8
#define U_REC 131072    // 1024*1024/8

__global__ __launch_bounds__(256) void cast_small_kernel(
    const float* __restrict__ pW1, const float* __restrict__ pW2,
    const float* __restrict__ recW,
    unsigned short* __restrict__ pW1b, unsigned short* __restrict__ pW2b,
    unsigned short* __restrict__ recWb) {
  long u = (long)blockIdx.x * 256 + threadIdx.x;
  const float* src;
  unsigned short* dst;
  if (u < U_PW1) { src = pW1 + u * 8; dst = pW1b + u * 8; }
  else if (u < U_PW1 + U_PW2) {
    long t = u - U_PW1;
    int l = (int)(t / 8192), r = (int)((t % 8192) / 128), kg = (int)(t % 128);
    src = pW2 + (((size_t)l * NW_ + r) * HD_ + kg * 8);
    dst = pW2b + (((size_t)l * 128 + r) * HD_ + kg * 8);
  } else {
    long t = u - U_PW1 - U_PW2;
    src = recW + t * 8; dst = recWb + t * 8;
  }
  *reinterpret_cast<short8*>(dst) =
      pack8(*reinterpret_cast<const f32x4*>(src),
            *reinterpret_cast<const f32x4*>(src + 4));
}

// ---------------------------------------------------------------------------
// Setup 3: A slabs (h=0 || z bf16), h32 zero, gate-constant table
// gateC[L][7][HD]: wtr, wtu, wtn, br(=bih+bhh), bu, bxn, bhn
// ---------------------------------------------------------------------------
__global__ __launch_bounds__(256) void init_misc_kernel(
    const float* __restrict__ z, const float* __restrict__ Wih,
    const float* __restrict__ bih, const float* __restrict__ bhh,
    unsigned short* __restrict__ Abuf, float* __restrict__ h32,
    float* __restrict__ gateC) {
  long idx = (long)blockIdx.x * 256 + threadIdx.x;
  const long N1 = (long)B_ * KA_;            // 1,310,720
  const long N2 = (long)L_ * 7 * HD_;        // 229,376
  if (idx < N1) {
    int b = (int)(idx / KA_), c = (int)(idx % KA_);
    unsigned short v = 0;
    if (c >= HD_) v = f2bf(z[(size_t)b * ZD_ + (c - HD_)]);
    Abuf[idx] = v;
    Abuf[N1 + idx] = v;
    if (c < HD_) h32[(size_t)b * HD_ + c] = 0.f;
  } else if (idx < N1 + N2) {
    long i2 = idx - N1;
    int n = (int)(i2 & 1023);
    int row = (int)(i2 >> 10);
    int l = row / 7, rr = row % 7;
    size_t g3 = (size_t)l * THD_;
    float v;
    if (rr == 0) v = Wih[(g3 + n) * 257 + 256];
    else if (rr == 1) v = Wih[(g3 + 1024 + n) * 257 + 256];
    else if (rr == 2) v = Wih[(g3 + 2048 + n) * 257 + 256];
    else if (rr == 3) v = bih[g3 + n] + bhh[g3 + n];
    else if (rr == 4) v = bih[g3 + 1024 + n] + bhh[g3 + 1024 + n];
    else if (rr == 5) v = bih[g3 + 2048 + n];
    else v = bhh[g3 + 2048 + n];
    gateC[((size_t)l * 7 + rr) * HD_ + n] = v;
  }
}

// ---------------------------------------------------------------------------
// bf16 x bf16 GEMM, 128x128 tile, BK=64, global_load_lds staging with XOR
// k-group swizzle (lane-linear LDS dest; slot g at row r holds global
// k-group g^(r&7)), single-buffer 2-barrier K-loop.
// EPI: 0 = +bias, relu -> bf16 out; 1 = +bias, sigmoid -> f32;
//      2 = +bias, sigmoid -> f32 transposed [NW,B,L] (guard n<64);
//      3 = raw f32 store (GRU step; kt range skips structural zeros)
// ---------------------------------------------------------------------------
template <int EPI>
__global__ __launch_bounds__(256) void gemm_bb_kernel(
    const unsigned short* __restrict__ Abase, long strideA, int lda,
    const unsigned short* __restrict__ Bbase, long strideB, int ldb,
    const float* __restrict__ biasBase, int strideBias,
    float* __restrict__ outBase, long strideOut, int ldo, int K64) {
  __shared__ __align__(16) unsigned short ldsA[128 * 64];   // [r][slot][8]
  __shared__ __align__(16) unsigned short ldsB[128 * 64];
  const int tid = threadIdx.x, lane = tid & 63, w = tid >> 6;
  const int wm = w & 1, wn = w >> 1;
  const int nb = blockIdx.x * 128, mb = blockIdx.y * 128;
  const int lz = blockIdx.z;
  const unsigned short* A = Abase + (long)lz * strideA;
  const unsigned short* Bw = Bbase + (long)lz * strideB;

  int ktLo = 0, ktHi = K64;
  if constexpr (EPI == 3) {
    if (nb >= 3072) ktLo = 16;
    else if (nb >= 2048) ktHi = 16;
  }

  f32x4 zf = {0.f, 0.f, 0.f, 0.f};
  f32x4 acc[4][4];
#pragma unroll
  for (int i = 0; i < 4; ++i)
#pragma unroll
    for (int j = 0; j < 4; ++j) acc[i][j] = zf;

  // staging indices: unit i = tid + j*256 covers (r = i>>3, slot g = i&7)
  const int sr = tid >> 3, sg = tid & 7;
  const int q = lane >> 4, cc = lane & 15;

  for (int kt = ktLo; kt < ktHi; ++kt) {
    const int k0 = kt * 64;
#pragma unroll
    for (int j = 0; j < 4; ++j) {
      int r = sr + j * 32;
      int gg = sg ^ (r & 7);                      // global k-group for this slot
      async_load16(A + (size_t)(mb + r) * lda + k0 + gg * 8,
                   &ldsA[(size_t)(tid + j * 256) * 8]);
    }
#pragma unroll
    for (int j = 0; j < 4; ++j) {
      int r = sr + j * 32;
      int gg = sg ^ (r & 7);
      async_load16(Bw + (size_t)(nb + r) * ldb + k0 + gg * 8,
                   &ldsB[(size_t)(tid + j * 256) * 8]);
    }
    __syncthreads();
#pragma unroll
    for (int ks = 0; ks < 2; ++ks) {
      const int kq = ks * 4 + q;
      short8 a[4], b[4];
#pragma unroll
      for (int i = 0; i < 4; ++i) {
        int r = wm * 64 + i * 16 + cc;
        a[i] = *(const short8*)&ldsA[(size_t)(r * 8 + (kq ^ (r & 7))) * 8];
      }
#pragma unroll
      for (int j = 0; j < 4; ++j) {
        int n = wn * 64 + j * 16 + cc;
        b[j] = *(const short8*)&ldsB[(size_t)(n * 8 + (kq ^ (n & 7))) * 8];
      }
#pragma unroll
      for (int i = 0; i < 4; ++i)
#pragma unroll
        for (int j = 0; j < 4; ++j) acc[i][j] = mfma16(a[i], b[j], acc[i][j]);
    }
    __syncthreads();
  }

#pragma unroll
  for (int j = 0; j < 4; ++j) {
    int n = nb + wn * 64 + j * 16 + cc;
    float bv = 0.f;
    if constexpr (EPI == 0 || EPI == 1) bv = biasBase[(size_t)lz * strideBias + n];
    if constexpr (EPI == 2) bv = (n < NW_) ? biasBase[(size_t)lz * strideBias + n] : 0.f;
#pragma unroll
    for (int i = 0; i < 4; ++i) {
#pragma unroll
      for (int r = 0; r < 4; ++r) {
        int m = mb + wm * 64 + i * 16 + q * 4 + r;
        float v = acc[i][j][r] + bv;
        if constexpr (EPI == 0) {
          v = fmaxf(v, 0.f);
          reinterpret_cast<unsigned short*>(outBase)[(size_t)lz * strideOut + (size_t)m * ldo + n] = f2bf(v);
        } else if constexpr (EPI == 1) {
          outBase[(size_t)m * ldo + n] = sig_(v);
        } else if constexpr (EPI == 2) {
          if (n < NW_) outBase[((size_t)n * B_ + m) * L_ + lz] = sig_(v);
        } else {
          outBase[(size_t)m * ldo + n] = v;
        }
      }
    }
  }
}

// ---------------------------------------------------------------------------
// GRU elementwise epilogue: P[1024,4096] (r,u,hn,xn) -> h update
// ---------------------------------------------------------------------------
__global__ __launch_bounds__(256) void gru_epi_kernel(
    const float* __restrict__ P, const float* __restrict__ gateC,
    const float* __restrict__ tmat, const float* __restrict__ eps,
    float* __restrict__ h32, unsigned short* __restrict__ Anext,
    unsigned short* __restrict__ hist, int l) {
  int idx = blockIdx.x * 256 + threadIdx.x;     // B*HD/4 threads
  int m = idx >> 8, n4 = (idx & 255) << 2;
  const float* gl = gateC + (size_t)l * 7 * HD_;
  const float* Pm = P + (size_t)m * NB_;
  f32x4 pr = *(const f32x4*)&Pm[n4];
  f32x4 pu = *(const f32x4*)&Pm[1024 + n4];
  f32x4 ph = *(const f32x4*)&Pm[2048 + n4];
  f32x4 px = *(const f32x4*)&Pm[3072 + n4];
  f32x4 wtr = *(const f32x4*)&gl[n4];
  f32x4 wtu = *(const f32x4*)&gl[1024 + n4];
  f32x4 wtn = *(const f32x4*)&gl[2048 + n4];
  f32x4 br  = *(const f32x4*)&gl[3072 + n4];
  f32x4 bu  = *(const f32x4*)&gl[4096 + n4];
  f32x4 bxn = *(const f32x4*)&gl[5120 + n4];
  f32x4 bhn = *(const f32x4*)&gl[6144 + n4];
  float tb = tmat[(size_t)m * L_ + l];
  size_t ho = (size_t)m * HD_ + n4;
  f32x4 h = *(const f32x4*)&h32[ho];
  f32x4 ep = *(const f32x4*)&eps[(size_t)l * B_ * HD_ + ho];
  const float std_ = 1.0025031f;  // exp(0.5*0.005)
  ushort4 hb;
  unsigned short* hbp = &hb.x;
#pragma unroll
  for (int c = 0; c < 4; ++c) {
    float rv = sig_(pr[c] + tb * wtr[c] + br[c]);
    float uv = sig_(pu[c] + tb * wtu[c] + bu[c]);
    float nv = tanh_(px[c] + tb * wtn[c] + bxn[c] + rv * (ph[c] + bhn[c]));
    float hn = (1.0f - uv) * nv + uv * h[c] + std_ * ep[c];
    h[c] = hn;
    hbp[c] = f2bf(hn);
  }
  *(f32x4*)&h32[ho] = h;
  *(ushort4*)&Anext[(size_t)m * KA_ + n4] = hb;
  *(ushort4*)&hist[(size_t)l * B_ * HD_ + ho] = hb;
}

// ---------------------------------------------------------------------------
extern "C" void kernel_launch(void* const* d_in, const int* in_sizes, int n_in,
                              void* d_out, int out_size, void* d_ws, size_t ws_size,
                              hipStream_t stream) {
  const float* z    = (const float*)d_in[0];
  const float* tmat = (const float*)d_in[1];
  const float* eps  = (const float*)d_in[2];
  const float* Wih  = (const float*)d_in[3];
  const float* Whh  = (const float*)d_in[4];
  const float* bih  = (const float*)d_in[5];
  const float* bhh  = (const float*)d_in[6];
  const float* pW1  = (const float*)d_in[7];
  const float* pb1  = (const float*)d_in[8];
  const float* pW2  = (const float*)d_in[9];
  const float* pb2  = (const float*)d_in[10];
  const float* recW = (const float*)d_in[11];
  const float* recb = (const float*)d_in[12];
  float* out = (float*)d_out;

  char* ws = (char*)d_ws;
  unsigned short* Abuf  = (unsigned short*)(ws);               // 5,242,880
  float*          h32   = (float*)(ws + 5242880);              // 4,194,304
  unsigned short* hist  = (unsigned short*)(ws + 9437184);     // 67,108,864
  unsigned short* act   = (unsigned short*)(ws + 76546048);    // 67,108,864
  float*          P     = (float*)(ws + 143654912);            // 16,777,216
  float*          gateC = (float*)(ws + 160432128);            // 917,504
  unsigned short* Bfull = (unsigned short*)(ws + 161349632);   // 335,544,320
  unsigned short* pW1b  = (unsigned short*)(ws + 496893952);   // 67,108,864
  unsigned short* pW2b  = (unsigned short*)(ws + 564002816);   // 8,388,608
  unsigned short* recWb = (unsigned short*)(ws + 572391424);   // 2,097,152
  // total: 574,488,576 bytes

  cast_bfull_kernel<<<61440, 256, 0, stream>>>(Whh, Wih, Bfull);
  cast_small_kernel<<<17920, 256, 0, stream>>>(pW1, pW2, recW, pW1b, pW2b, recWb);
  {
    long total = (long)B_ * KA_ + (long)L_ * 7 * HD_;
    init_misc_kernel<<<(int)((total + 255) / 256), 256, 0, stream>>>(
        z, Wih, bih, bhh, Abuf, h32, gateC);
  }
  for (int l = 0; l < L_; ++l) {
    const unsigned short* Acur = Abuf + (size_t)(l & 1) * B_ * KA_;
    unsigned short* Anext      = Abuf + (size_t)((l + 1) & 1) * B_ * KA_;
    gemm_bb_kernel<3><<<dim3(32, 8, 1), 256, 0, stream>>>(
        Acur, 0, KA_, Bfull + (size_t)l * NB_ * KA_, 0, KA_,
        nullptr, 0, P, 0, NB_, 20);
    gru_epi_kernel<<<1024, 256, 0, stream>>>(P, gateC, tmat, eps, h32, Anext, hist, l);
  }
  // MLP layer 1: act = relu(hist @ W1^T + b1) -> bf16, batched over L
  gemm_bb_kernel<0><<<dim3(8, 8, L_), 256, 0, stream>>>(
      hist, (long)B_ * HD_, HD_, pW1b, (long)HD_ * HD_, HD_, pb1, HD_,
      (float*)act, (long)B_ * HD_, HD_, 16);
  // MLP layer 2: preds -> transposed [NW, B, L] region of d_out
  gemm_bb_kernel<2><<<dim3(1, 8, L_), 256, 0, stream>>>(
      act, (long)B_ * HD_, HD_, pW2b, (long)128 * HD_, HD_, pb2, NW_,
      out + (size_t)B_ * XD_, 0, 0, 16);
  // recon = sigmoid(h_T @ recW^T + recb)
  gemm_bb_kernel<1><<<dim3(8, 8, 1), 256, 0, stream>>>(
      hist + (size_t)(L_ - 1) * B_ * HD_, 0, HD_, recWb, 0, HD_, recb, 0,
      out, 0, XD_, 16);
}